// Round 7
// baseline (651.913 us; speedup 1.0000x reference)
//
#include <hip/hip_runtime.h>
#include <hip/hip_bf16.h>

static constexpr int NN = 50000;   // nodes
static constexpr int NE = 800000;  // edges
static constexpr int NG = 512;     // graphs
static constexpr int NB = 196;     // node blocks: 196*256 >= NN

// cooperative-style kernel geometry: 1024 blocks x 256 thr = 4 blocks/CU x 256 CUs,
// guaranteed co-resident via __launch_bounds__(256,4) + LDS <= 40KB.
static constexpr int GRID = 1024;
static constexpr int GB = 391;               // gemm-role blocks (2 tiles each -> 782 tiles)
static constexpr int HB = GRID - GB;         // 633 hist-role blocks
static constexpr int HTHREADS = HB * 256;    // 162048
static constexpr int KPT = 5;                // ceil(NE / HTHREADS)
static constexpr int NTILES = (NN + 63) / 64;  // 782

__device__ __forceinline__ float bfu(ushort u) {
    return __uint_as_float((unsigned)u << 16);
}
__device__ __forceinline__ ushort fbf(float f) {
    return __hip_bfloat16_raw(__float2bfloat16(f)).x;
}

// grid-wide barrier: monotonically increasing target, bar pre-zeroed by zero_kernel
__device__ __forceinline__ void gsync(int* bar, int target) {
    __syncthreads();
    if (threadIdx.x == 0) {
        __threadfence();                     // release: flush my writes (device scope)
        atomicAdd(bar, 1);
        while (__hip_atomic_load(bar, __ATOMIC_RELAXED, __HIP_MEMORY_SCOPE_AGENT) < target) {}
        __threadfence();                     // acquire
    }
    __syncthreads();
}

__global__ void zero_kernel(float* __restrict__ p, int n) {
    int i = blockIdx.x * blockDim.x + threadIdx.x;
    if (i < n) p[i] = 0.f;
}

// ---------------- gemm128 body (coop phase B): X fp32 @ W1(bf16 LDS) -> xw1 bf16 ------
__device__ __forceinline__ void gemm128_body(const float* __restrict__ X,
                                             ushort* __restrict__ out,
                                             int row0, float (*Xs)[68],
                                             const ushort* __restrict__ Wsb) {
    int tx = threadIdx.x & 15, ty = threadIdx.x >> 4;
    float acc[4][4] = {};
    for (int kb = 0; kb < 128; kb += 64) {
        __syncthreads();
        for (int i = threadIdx.x; i < 1024; i += 256) {   // 64 rows x 16 float4
            int r = i >> 4, k4 = i & 15;
            int gr = row0 + r; if (gr >= NN) gr = NN - 1;
            *(float4*)&Xs[r][k4 * 4] = *(const float4*)(X + (long long)gr * 128 + kb + k4 * 4);
        }
        __syncthreads();
#pragma unroll
        for (int k4 = 0; k4 < 16; ++k4) {
            float4 x0 = *(const float4*)&Xs[ty * 4 + 0][k4 * 4];
            float4 x1 = *(const float4*)&Xs[ty * 4 + 1][k4 * 4];
            float4 x2 = *(const float4*)&Xs[ty * 4 + 2][k4 * 4];
            float4 x3 = *(const float4*)&Xs[ty * 4 + 3][k4 * 4];
#pragma unroll
            for (int kk = 0; kk < 4; ++kk) {
                uint2 wu = *(const uint2*)&Wsb[(kb + k4 * 4 + kk) * 64 + tx * 4];
                float w0 = __uint_as_float(wu.x << 16);
                float w1 = __uint_as_float(wu.x & 0xffff0000u);
                float w2 = __uint_as_float(wu.y << 16);
                float w3 = __uint_as_float(wu.y & 0xffff0000u);
                float xa = (&x0.x)[kk], xb = (&x1.x)[kk], xc = (&x2.x)[kk], xd = (&x3.x)[kk];
                acc[0][0] = fmaf(xa, w0, acc[0][0]); acc[0][1] = fmaf(xa, w1, acc[0][1]);
                acc[0][2] = fmaf(xa, w2, acc[0][2]); acc[0][3] = fmaf(xa, w3, acc[0][3]);
                acc[1][0] = fmaf(xb, w0, acc[1][0]); acc[1][1] = fmaf(xb, w1, acc[1][1]);
                acc[1][2] = fmaf(xb, w2, acc[1][2]); acc[1][3] = fmaf(xb, w3, acc[1][3]);
                acc[2][0] = fmaf(xc, w0, acc[2][0]); acc[2][1] = fmaf(xc, w1, acc[2][1]);
                acc[2][2] = fmaf(xc, w2, acc[2][2]); acc[2][3] = fmaf(xc, w3, acc[2][3]);
                acc[3][0] = fmaf(xd, w0, acc[3][0]); acc[3][1] = fmaf(xd, w1, acc[3][1]);
                acc[3][2] = fmaf(xd, w2, acc[3][2]); acc[3][3] = fmaf(xd, w3, acc[3][3]);
            }
        }
    }
#pragma unroll
    for (int j = 0; j < 4; ++j) {
        int r = row0 + ty * 4 + j;
        if (r < NN) {
            ushort4 sv;
            sv.x = fbf(acc[j][0]); sv.y = fbf(acc[j][1]);
            sv.z = fbf(acc[j][2]); sv.w = fbf(acc[j][3]);
            *(ushort4*)(out + (long long)r * 64 + tx * 4) = sv;
        }
    }
}

__device__ __forceinline__ int block_scan_inclusive(int v, int* wtot) {
    int lane = threadIdx.x & 63, wid = threadIdx.x >> 6;
    int inc = v;
#pragma unroll
    for (int off = 1; off < 64; off <<= 1) {
        int n = __shfl_up(inc, (unsigned)off, 64);
        if (lane >= off) inc += n;
    }
    if (lane == 63) wtot[wid] = inc;
    __syncthreads();
    int add = 0;
    for (int w = 0; w < wid; ++w) add += wtot[w];
    return inc + add;
}

// ---------------- the fused CSR-build + gemm128 kernel --------------------------------
// phase B: blocks [0,GB) gemm x@W1 || blocks [GB,GRID) 64-bit atomic histogram
// phase C: dinv + per-block count partials     phase D: rowptr scan + graph bounds
// phase E: scatter epack using rank values still held in registers
__global__ __launch_bounds__(256, 4) void coop_kernel(
    const int* __restrict__ src, const int* __restrict__ dst,
    const float* __restrict__ ew, const int* __restrict__ batch,
    const float* __restrict__ X, const float* __restrict__ W1,
    unsigned long long* __restrict__ h, float* __restrict__ dinv,
    int* __restrict__ rowptr, int* __restrict__ partial,
    int* __restrict__ gbeg, int* __restrict__ gend,
    int2* __restrict__ epack, ushort* __restrict__ xw1, int* __restrict__ bar) {
    __shared__ float Xs[64][68];        // 17408 B
    __shared__ ushort Wsb[128 * 64];    // 16384 B  (total 33.8 KB <= 40 KB for 4/CU)
    __shared__ int wtot[4];
    __shared__ int poff_s;
    int bid = blockIdx.x, t = threadIdx.x;
    int rank[KPT];

    // ---- phase B ----
    if (bid < GB) {
        for (int i = t; i < 128 * 16; i += 256) {        // stage W1 -> bf16 LDS
            float4 w = ((const float4*)W1)[i];
            ushort4 s; s.x = fbf(w.x); s.y = fbf(w.y); s.z = fbf(w.z); s.w = fbf(w.w);
            *(ushort4*)&Wsb[i * 4] = s;
        }
        for (int tile = bid; tile < NTILES; tile += GB)  // body's syncthreads fences Wsb
            gemm128_body(X, xw1, tile * 64, Xs, Wsb);
    } else {
        int ht = (bid - GB) * 256 + t;
#pragma unroll
        for (int k = 0; k < KPT; ++k) {
            int e = ht + k * HTHREADS;
            if (e < NE) {
                int d = dst[e];
                unsigned int fx = __float2uint_rn(ew[e] * 1048576.0f);
                unsigned long long old = atomicAdd(&h[d], (1ULL << 40) | (unsigned long long)fx);
                rank[k] = (int)(old >> 40);
            }
        }
    }
    gsync(bar, GRID);

    // ---- phase C: dinv + partials (blocks 0..NB-1) ----
    if (bid < NB) {
        int i = bid * 256 + t;
        int cnt = 0;
        if (i < NN) {
            unsigned long long v = h[i];
            cnt = (int)(v >> 40);
            float deg = (float)(v & ((1ULL << 40) - 1)) * (1.0f / 1048576.0f) + 1.0f;
            dinv[i] = 1.0f / sqrtf(deg);
        }
        int lane = t & 63, wid = t >> 6;
        int v = cnt;
#pragma unroll
        for (int off = 32; off > 0; off >>= 1) v += __shfl_down(v, (unsigned)off, 64);
        if (lane == 0) wtot[wid] = v;
        __syncthreads();
        if (t == 0) partial[bid] = wtot[0] + wtot[1] + wtot[2] + wtot[3];
    }
    gsync(bar, 2 * GRID);

    // ---- phase D: rowptr + graph bounds (blocks 0..NB-1) ----
    if (bid < NB) {
        if (t < 64) {            // wave 0: exclusive offset of this block
            int s = 0;
            for (int i2 = t; i2 < bid; i2 += 64) s += partial[i2];
#pragma unroll
            for (int off = 32; off > 0; off >>= 1) s += __shfl_down(s, (unsigned)off, 64);
            if (t == 0) poff_s = s;
        }
        int i = bid * 256 + t;
        int v = (i < NN) ? (int)(h[i] >> 40) : 0;
        int incl = block_scan_inclusive(v, wtot);   // internal syncthreads covers poff_s
        if (i < NN) {
            rowptr[i + 1] = poff_s + incl;
            int g = batch[i];
            if (i == 0 || batch[i - 1] != g) gbeg[g] = i;
            if (i == NN - 1 || batch[i + 1] != g) gend[g] = i + 1;
        }
        if (i == 0) rowptr[0] = 0;
    }
    gsync(bar, 3 * GRID);

    // ---- phase E: scatter (hist-role blocks, ranks still in registers) ----
    if (bid >= GB) {
        int ht = (bid - GB) * 256 + t;
#pragma unroll
        for (int k = 0; k < KPT; ++k) {
            int e = ht + k * HTHREADS;
            if (e < NE) {
                int s = src[e], d = dst[e];
                int pos = rowptr[d] + rank[k];
                epack[pos] = make_int2(s, __float_as_int(dinv[s] * ew[e]));
            }
        }
    }
}

// ---------------- standalone GEMM (layer 2): h1 bf16 @ W2 fp32 -> xw2 bf16 -----------
__global__ __launch_bounds__(256) void gemm64_kernel(const ushort* __restrict__ X,
                                                     const float* __restrict__ W,
                                                     ushort* __restrict__ out) {
    __shared__ float Xs[64][68];
    __shared__ float Ws[64 * 64];
    for (int i = threadIdx.x; i < 64 * 16; i += 256)
        ((float4*)Ws)[i] = ((const float4*)W)[i];
    int tx = threadIdx.x & 15, ty = threadIdx.x >> 4;
    int row0 = blockIdx.x * 64;
    float acc[4][4] = {};
    __syncthreads();
    for (int i = threadIdx.x; i < 512; i += 256) {   // 64 rows x 8 groups of 8 ch
        int r = i >> 3, g = i & 7;
        int gr = row0 + r; if (gr >= NN) gr = NN - 1;
        uint4 v = *(const uint4*)(X + (long long)gr * 64 + g * 8);
        float4 f0, f1;
        f0.x = __uint_as_float(v.x << 16); f0.y = __uint_as_float(v.x & 0xffff0000u);
        f0.z = __uint_as_float(v.y << 16); f0.w = __uint_as_float(v.y & 0xffff0000u);
        f1.x = __uint_as_float(v.z << 16); f1.y = __uint_as_float(v.z & 0xffff0000u);
        f1.z = __uint_as_float(v.w << 16); f1.w = __uint_as_float(v.w & 0xffff0000u);
        *(float4*)&Xs[r][g * 8] = f0;
        *(float4*)&Xs[r][g * 8 + 4] = f1;
    }
    __syncthreads();
#pragma unroll
    for (int k4 = 0; k4 < 16; ++k4) {
        float4 x0 = *(const float4*)&Xs[ty * 4 + 0][k4 * 4];
        float4 x1 = *(const float4*)&Xs[ty * 4 + 1][k4 * 4];
        float4 x2 = *(const float4*)&Xs[ty * 4 + 2][k4 * 4];
        float4 x3 = *(const float4*)&Xs[ty * 4 + 3][k4 * 4];
#pragma unroll
        for (int kk = 0; kk < 4; ++kk) {
            float4 wv = *(const float4*)&Ws[(k4 * 4 + kk) * 64 + tx * 4];
            float xa = (&x0.x)[kk], xb = (&x1.x)[kk], xc = (&x2.x)[kk], xd = (&x3.x)[kk];
            acc[0][0] = fmaf(xa, wv.x, acc[0][0]); acc[0][1] = fmaf(xa, wv.y, acc[0][1]);
            acc[0][2] = fmaf(xa, wv.z, acc[0][2]); acc[0][3] = fmaf(xa, wv.w, acc[0][3]);
            acc[1][0] = fmaf(xb, wv.x, acc[1][0]); acc[1][1] = fmaf(xb, wv.y, acc[1][1]);
            acc[1][2] = fmaf(xb, wv.z, acc[1][2]); acc[1][3] = fmaf(xb, wv.w, acc[1][3]);
            acc[2][0] = fmaf(xc, wv.x, acc[2][0]); acc[2][1] = fmaf(xc, wv.y, acc[2][1]);
            acc[2][2] = fmaf(xc, wv.z, acc[2][2]); acc[2][3] = fmaf(xc, wv.w, acc[2][3]);
            acc[3][0] = fmaf(xd, wv.x, acc[3][0]); acc[3][1] = fmaf(xd, wv.y, acc[3][1]);
            acc[3][2] = fmaf(xd, wv.z, acc[3][2]); acc[3][3] = fmaf(xd, wv.w, acc[3][3]);
        }
    }
#pragma unroll
    for (int j = 0; j < 4; ++j) {
        int r = row0 + ty * 4 + j;
        if (r < NN) {
            ushort4 sv;
            sv.x = fbf(acc[j][0]); sv.y = fbf(acc[j][1]);
            sv.z = fbf(acc[j][2]); sv.w = fbf(acc[j][3]);
            *(ushort4*)(out + (long long)r * 64 + tx * 4) = sv;
        }
    }
}

// ---------------- CSR aggregation: one wave per node; quarter-waves x 4 ch/lane -------
template <bool RELU>
__global__ __launch_bounds__(256) void agg_kernel(const ushort* __restrict__ xw,
                                                  const int* __restrict__ rowptr,
                                                  const int2* __restrict__ epack,
                                                  const float* __restrict__ dinv,
                                                  const float* __restrict__ bias,
                                                  ushort* __restrict__ out) {
    int node = blockIdx.x * 4 + (threadIdx.x >> 6);
    if (node >= NN) return;
    int lane = threadIdx.x & 63;
    int q = lane >> 4;       // edge slot within group of 4
    int l = lane & 15;       // channel group: ch 4l..4l+3
    int beg = rowptr[node], end = rowptr[node + 1];
    float a0 = 0.f, a1 = 0.f, a2 = 0.f, a3 = 0.f;
    float b0 = 0.f, b1 = 0.f, b2 = 0.f, b3 = 0.f;
    int j = beg + q;
    for (; j + 4 < end; j += 8) {
        int2 pA = epack[j];
        int2 pB = epack[j + 4];
        ushort4 uA = *(const ushort4*)(xw + pA.x * 64 + 4 * l);
        ushort4 uB = *(const ushort4*)(xw + pB.x * 64 + 4 * l);
        float wA = __int_as_float(pA.y);
        float wB = __int_as_float(pB.y);
        a0 = fmaf(wA, bfu(uA.x), a0); a1 = fmaf(wA, bfu(uA.y), a1);
        a2 = fmaf(wA, bfu(uA.z), a2); a3 = fmaf(wA, bfu(uA.w), a3);
        b0 = fmaf(wB, bfu(uB.x), b0); b1 = fmaf(wB, bfu(uB.y), b1);
        b2 = fmaf(wB, bfu(uB.z), b2); b3 = fmaf(wB, bfu(uB.w), b3);
    }
    if (j < end) {
        int2 pA = epack[j];
        ushort4 uA = *(const ushort4*)(xw + pA.x * 64 + 4 * l);
        float wA = __int_as_float(pA.y);
        a0 = fmaf(wA, bfu(uA.x), a0); a1 = fmaf(wA, bfu(uA.y), a1);
        a2 = fmaf(wA, bfu(uA.z), a2); a3 = fmaf(wA, bfu(uA.w), a3);
    }
    a0 += b0; a1 += b1; a2 += b2; a3 += b3;
    a0 += __shfl_xor(a0, 16); a0 += __shfl_xor(a0, 32);
    a1 += __shfl_xor(a1, 16); a1 += __shfl_xor(a1, 32);
    a2 += __shfl_xor(a2, 16); a2 += __shfl_xor(a2, 32);
    a3 += __shfl_xor(a3, 16); a3 += __shfl_xor(a3, 32);
    if (q == 0) {
        float di = dinv[node];
        float d2 = di * di;
        ushort4 us = *(const ushort4*)(xw + node * 64 + 4 * l);
        float4 bv = *(const float4*)(bias + 4 * l);
        float o0 = fmaf(di, a0, fmaf(d2, bfu(us.x), bv.x));
        float o1 = fmaf(di, a1, fmaf(d2, bfu(us.y), bv.y));
        float o2 = fmaf(di, a2, fmaf(d2, bfu(us.z), bv.z));
        float o3 = fmaf(di, a3, fmaf(d2, bfu(us.w), bv.w));
        if (RELU) {
            o0 = fmaxf(o0, 0.f); o1 = fmaxf(o1, 0.f);
            o2 = fmaxf(o2, 0.f); o3 = fmaxf(o3, 0.f);
        }
        ushort4 sv;
        sv.x = fbf(o0); sv.y = fbf(o1); sv.z = fbf(o2); sv.w = fbf(o3);
        *(ushort4*)(out + node * 64 + 4 * l) = sv;
    }
}

// ---------------- fused mean-pool + MLP head: 4 waves per graph (h is bf16) -----------
__global__ __launch_bounds__(256) void poolhead_kernel(const ushort* __restrict__ h,
                                                       const int* __restrict__ gbeg,
                                                       const int* __restrict__ gend,
                                                       const float* __restrict__ LW1,
                                                       const float* __restrict__ Lb1,
                                                       const float* __restrict__ LW2,
                                                       const float* __restrict__ Lb2,
                                                       float* __restrict__ out) {
    __shared__ float pp[4][64];
    __shared__ float p[64];
    __shared__ float t1[32];
    int g = blockIdx.x, t = threadIdx.x;
    int lane = t & 63, wid = t >> 6;
    int b = gbeg[g], e = gend[g];
    float acc = 0.f;
    for (int i = b + wid; i < e; i += 4) acc += bfu(h[i * 64 + lane]);
    pp[wid][lane] = acc;
    __syncthreads();
    if (t < 64) {
        float s = pp[0][t] + pp[1][t] + pp[2][t] + pp[3][t];
        p[t] = s / fmaxf((float)(e - b), 1.0f);
    }
    __syncthreads();
    if (t < 32) {
        float a = Lb1[t];
#pragma unroll
        for (int k = 0; k < 64; ++k) a = fmaf(p[k], LW1[k * 32 + t], a);
        t1[t] = a;
    }
    __syncthreads();
    if (t < 10) {
        float a = Lb2[t];
#pragma unroll
        for (int j = 0; j < 32; ++j) a = fmaf(t1[j], LW2[j * 10 + t], a);
        out[g * 10 + t] = a;
    }
}

// ---------------- launch ----------------

extern "C" void kernel_launch(void* const* d_in, const int* in_sizes, int n_in,
                              void* d_out, int out_size, void* d_ws, size_t ws_size,
                              hipStream_t stream) {
    const float* x     = (const float*)d_in[0];
    const int*   ei    = (const int*)d_in[1];   // [2, NE]
    const float* ew    = (const float*)d_in[2];
    const int*   batch = (const int*)d_in[3];
    const float* W1    = (const float*)d_in[4];
    const float* b1    = (const float*)d_in[5];
    const float* W2    = (const float*)d_in[6];
    const float* b2    = (const float*)d_in[7];
    const float* LW1   = (const float*)d_in[8];
    const float* Lb1   = (const float*)d_in[9];
    const float* LW2   = (const float*)d_in[10];
    const float* Lb2   = (const float*)d_in[11];

    const int* src = ei;
    const int* dst = ei + NE;

    // workspace layout (4-byte units)
    float* ws = (float*)d_ws;
    unsigned long long* h64 = (unsigned long long*)ws;  // [NN] ull: 0 .. 100096
    int*   gbeg   = (int*)(ws + 100096);       // [NG] -> 100608
    int*   gend   = (int*)(ws + 100608);       // [NG] -> 101120
    int*   bar    = (int*)(ws + 101120);       // [1]  (zero range ends at 101376)
    float* dinv   = ws + 101376;               // [NN]   -> 151424
    int*   rowptr = (int*)(ws + 151424);       // [NN+1] -> 201472
    int*   partial= (int*)(ws + 201472);       // [NB..] -> 202496
    int2*  epack  = (int2*)(ws + 202496);      // [NE]   -> 1802496 (8B aligned)
    ushort* xwA   = (ushort*)(ws + 1802496);   // [NN*64] bf16: xw1, later xw2 -> 3402496
    ushort* h12   = (ushort*)(ws + 3402496);   // [NN*64] bf16: h1, later h2 -> 5002496
    // total 5002496 floats = 20.0 MB

    // zero h64 + gbeg + gend + bar (bar MUST be zero before coop_kernel starts)
    zero_kernel<<<(101376 + 255) / 256, 256, 0, stream>>>(ws, 101376);

    // fused: hist||gemm128 -> dinv/partials -> rowptr/bounds -> scatter
    coop_kernel<<<GRID, 256, 0, stream>>>(src, dst, ew, batch, x, W1, h64, dinv,
                                          rowptr, partial, gbeg, gend, epack, xwA, bar);

    // ---- layer 1 aggregation ----
    agg_kernel<true><<<(NN + 3) / 4, 256, 0, stream>>>(xwA, rowptr, epack, dinv, b1, h12);

    // ---- layer 2 ----
    gemm64_kernel<<<NTILES, 256, 0, stream>>>(h12, W2, xwA);
    agg_kernel<false><<<(NN + 3) / 4, 256, 0, stream>>>(xwA, rowptr, epack, dinv, b2, h12);

    // ---- pool + head ----
    poolhead_kernel<<<NG, 256, 0, stream>>>(h12, gbeg, gend, LW1, Lb1, LW2, Lb2, (float*)d_out);
}

// Round 8
// 249.732 us; speedup vs baseline: 2.6105x; 2.6105x over previous
//
#include <hip/hip_runtime.h>
#include <hip/hip_bf16.h>

static constexpr int NN = 50000;   // nodes
static constexpr int NE = 800000;  // edges
static constexpr int NG = 512;     // graphs
static constexpr int NB = 196;     // node blocks: 196*256 >= NN
static constexpr int NTILES = (NN + 63) / 64;   // 782 gemm tiles
static constexpr int HG_GRID = 3910;            // 5*782: every 5th block (bid%5==2) is gemm

__device__ __forceinline__ float bfu(ushort u) {
    return __uint_as_float((unsigned)u << 16);
}
__device__ __forceinline__ ushort fbf(float f) {
    return __hip_bfloat16_raw(__float2bfloat16(f)).x;
}
__device__ __forceinline__ void bf8_unpack(uint4 u, float* f) {
    f[0] = __uint_as_float(u.x << 16); f[1] = __uint_as_float(u.x & 0xffff0000u);
    f[2] = __uint_as_float(u.y << 16); f[3] = __uint_as_float(u.y & 0xffff0000u);
    f[4] = __uint_as_float(u.z << 16); f[5] = __uint_as_float(u.z & 0xffff0000u);
    f[6] = __uint_as_float(u.w << 16); f[7] = __uint_as_float(u.w & 0xffff0000u);
}

__global__ void zero_kernel(float* __restrict__ p, int n) {
    int i = blockIdx.x * blockDim.x + threadIdx.x;
    if (i < n) p[i] = 0.f;
}

// ---------------- fused hist64 || gemm128, roles INTERLEAVED by blockIdx --------------
// bid%5==2 -> one 64-row gemm tile (x fp32 @ W1 bf16-LDS -> xw1 bf16)
// else     -> 256 edges of the 64-bit atomic histogram (count[40:64) | sum_ew fx20[0:40))
// Interleaving keeps both roles co-resident through the whole dispatch; LDS 34 KB
// allows 4 blocks/CU, so gemm hides under the hist atomic floor.
__global__ __launch_bounds__(256) void hist_gemm_kernel(const int* __restrict__ dst,
                                                        const float* __restrict__ ew,
                                                        unsigned long long* __restrict__ h,
                                                        int* __restrict__ rank,
                                                        const float* __restrict__ X,
                                                        const float* __restrict__ W1,
                                                        ushort* __restrict__ out) {
    __shared__ float Xs[64][68];        // 17408 B
    __shared__ ushort Wsb[128 * 64];    // 16384 B  (total 33.8 KB -> 4 blocks/CU)
    int bid = blockIdx.x, t = threadIdx.x;
    int m = bid % 5;
    if (m != 2) {
        // ---- hist role ----
        int ho = (bid / 5) * 4 + m - (m > 2 ? 1 : 0);   // 0..3127
        int e = ho * 256 + t;
        if (e < NE) {
            int d = dst[e];
            unsigned int fx = __float2uint_rn(ew[e] * 1048576.0f);
            unsigned long long old = atomicAdd(&h[d], (1ULL << 40) | (unsigned long long)fx);
            rank[e] = (int)(old >> 40);
        }
        return;
    }
    // ---- gemm role: tile (bid-2)/5 ----
    int row0 = ((bid - 2) / 5) * 64;
    for (int i = t; i < 128 * 16; i += 256) {       // stage W1 -> bf16 LDS
        float4 w = ((const float4*)W1)[i];
        ushort4 s; s.x = fbf(w.x); s.y = fbf(w.y); s.z = fbf(w.z); s.w = fbf(w.w);
        *(ushort4*)&Wsb[i * 4] = s;
    }
    int tx = t & 15, ty = t >> 4;
    float acc[4][4] = {};
    for (int kb = 0; kb < 128; kb += 64) {
        __syncthreads();
        for (int i = t; i < 1024; i += 256) {       // 64 rows x 16 float4
            int r = i >> 4, k4 = i & 15;
            int gr = row0 + r; if (gr >= NN) gr = NN - 1;
            *(float4*)&Xs[r][k4 * 4] = *(const float4*)(X + (long long)gr * 128 + kb + k4 * 4);
        }
        __syncthreads();
#pragma unroll
        for (int k4 = 0; k4 < 16; ++k4) {
            float4 x0 = *(const float4*)&Xs[ty * 4 + 0][k4 * 4];
            float4 x1 = *(const float4*)&Xs[ty * 4 + 1][k4 * 4];
            float4 x2 = *(const float4*)&Xs[ty * 4 + 2][k4 * 4];
            float4 x3 = *(const float4*)&Xs[ty * 4 + 3][k4 * 4];
#pragma unroll
            for (int kk = 0; kk < 4; ++kk) {
                uint2 wu = *(const uint2*)&Wsb[(kb + k4 * 4 + kk) * 64 + tx * 4];
                float w0 = __uint_as_float(wu.x << 16);
                float w1 = __uint_as_float(wu.x & 0xffff0000u);
                float w2 = __uint_as_float(wu.y << 16);
                float w3 = __uint_as_float(wu.y & 0xffff0000u);
                float xa = (&x0.x)[kk], xb = (&x1.x)[kk], xc = (&x2.x)[kk], xd = (&x3.x)[kk];
                acc[0][0] = fmaf(xa, w0, acc[0][0]); acc[0][1] = fmaf(xa, w1, acc[0][1]);
                acc[0][2] = fmaf(xa, w2, acc[0][2]); acc[0][3] = fmaf(xa, w3, acc[0][3]);
                acc[1][0] = fmaf(xb, w0, acc[1][0]); acc[1][1] = fmaf(xb, w1, acc[1][1]);
                acc[1][2] = fmaf(xb, w2, acc[1][2]); acc[1][3] = fmaf(xb, w3, acc[1][3]);
                acc[2][0] = fmaf(xc, w0, acc[2][0]); acc[2][1] = fmaf(xc, w1, acc[2][1]);
                acc[2][2] = fmaf(xc, w2, acc[2][2]); acc[2][3] = fmaf(xc, w3, acc[2][3]);
                acc[3][0] = fmaf(xd, w0, acc[3][0]); acc[3][1] = fmaf(xd, w1, acc[3][1]);
                acc[3][2] = fmaf(xd, w2, acc[3][2]); acc[3][3] = fmaf(xd, w3, acc[3][3]);
            }
        }
    }
#pragma unroll
    for (int j = 0; j < 4; ++j) {
        int r = row0 + ty * 4 + j;
        if (r < NN) {
            ushort4 sv;
            sv.x = fbf(acc[j][0]); sv.y = fbf(acc[j][1]);
            sv.z = fbf(acc[j][2]); sv.w = fbf(acc[j][3]);
            *(ushort4*)(out + (long long)r * 64 + tx * 4) = sv;
        }
    }
}

// fused: dinv computation + per-block count reduction (scan phase A)
__global__ __launch_bounds__(256) void dinv_scanA_kernel(const unsigned long long* __restrict__ h,
                                                         float* __restrict__ dinv,
                                                         int* __restrict__ partial) {
    int i = blockIdx.x * 256 + threadIdx.x;
    int cnt = 0;
    if (i < NN) {
        unsigned long long v = h[i];
        cnt = (int)(v >> 40);
        float deg = (float)(v & ((1ULL << 40) - 1)) * (1.0f / 1048576.0f) + 1.0f;
        dinv[i] = 1.0f / sqrtf(deg);
    }
    __shared__ int wsum[4];
    int lane = threadIdx.x & 63, wid = threadIdx.x >> 6;
    int v = cnt;
#pragma unroll
    for (int off = 32; off > 0; off >>= 1) v += __shfl_down(v, (unsigned)off, 64);
    if (lane == 0) wsum[wid] = v;
    __syncthreads();
    if (threadIdx.x == 0) partial[blockIdx.x] = wsum[0] + wsum[1] + wsum[2] + wsum[3];
}

__device__ __forceinline__ int block_scan_inclusive(int v, int* wtot) {
    int lane = threadIdx.x & 63, wid = threadIdx.x >> 6;
    int inc = v;
#pragma unroll
    for (int off = 1; off < 64; off <<= 1) {
        int n = __shfl_up(inc, (unsigned)off, 64);
        if (lane >= off) inc += n;
    }
    if (lane == 63) wtot[wid] = inc;
    __syncthreads();
    int add = 0;
    for (int w = 0; w < wid; ++w) add += wtot[w];
    return inc + add;
}

// fused: per-block prefix of partials + rowptr finalize + graph bounds
__global__ __launch_bounds__(256) void scanC_bounds_kernel(const unsigned long long* __restrict__ h,
                                                           const int* __restrict__ partial,
                                                           int* __restrict__ rowptr,
                                                           const int* __restrict__ batch,
                                                           int* __restrict__ gbeg,
                                                           int* __restrict__ gend) {
    __shared__ int wtot[4];
    __shared__ int poff_s;
    int t = threadIdx.x;
    if (t < 64) {   // wave 0: poff = sum partial[0..bid-1]
        int s = 0;
        for (int i = t; i < (int)blockIdx.x; i += 64) s += partial[i];
#pragma unroll
        for (int off = 32; off > 0; off >>= 1) s += __shfl_down(s, (unsigned)off, 64);
        if (t == 0) poff_s = s;
    }
    int i = blockIdx.x * 256 + t;
    int v = (i < NN) ? (int)(h[i] >> 40) : 0;
    int incl = block_scan_inclusive(v, wtot);   // internal __syncthreads covers poff_s
    if (i < NN) {
        rowptr[i + 1] = poff_s + incl;
        int g = batch[i];
        if (i == 0 || batch[i - 1] != g) gbeg[g] = i;
        if (i == NN - 1 || batch[i + 1] != g) gend[g] = i + 1;
    }
    if (i == 0) rowptr[0] = 0;
}

// Atomic-free scatter: pos = rowptr[d] + rank[e]; epack[pos] = (src, dinv[s]*ew)
__global__ __launch_bounds__(256) void scatter_kernel(const int* __restrict__ src,
                                                      const int* __restrict__ dst,
                                                      const float* __restrict__ ew,
                                                      const float* __restrict__ dinv,
                                                      const int* __restrict__ rowptr,
                                                      const int* __restrict__ rank,
                                                      int2* __restrict__ epack) {
    int e = blockIdx.x * blockDim.x + threadIdx.x;
    if (e >= NE) return;
    int s = src[e], d = dst[e];
    int pos = rowptr[d] + rank[e];
    float coef = dinv[s] * ew[e];
    epack[pos] = make_int2(s, __float_as_int(coef));
}

// ---------------- CSR aggregation: one wave per node; eighth-waves x 8 ch/lane --------
// out[i,:] = bias + dinv[i]^2*xw[i,:] + dinv[i] * sum_j (dinv[s]*ew)_j * xw[src_j,:]
template <bool RELU>
__global__ __launch_bounds__(256) void agg_kernel(const ushort* __restrict__ xw,
                                                  const int* __restrict__ rowptr,
                                                  const int2* __restrict__ epack,
                                                  const float* __restrict__ dinv,
                                                  const float* __restrict__ bias,
                                                  ushort* __restrict__ out) {
    int node = blockIdx.x * 4 + (threadIdx.x >> 6);
    if (node >= NN) return;
    int lane = threadIdx.x & 63;
    int slot = lane >> 3;    // edge slot within group of 8
    int l = lane & 7;        // channel group: ch 8l..8l+7 (uint4 = 16B/lane)
    int beg = rowptr[node], end = rowptr[node + 1];
    float a[8] = {}, b[8] = {};
    int j = beg + slot;
    for (; j + 8 < end; j += 16) {
        int2 pA = epack[j];
        int2 pB = epack[j + 8];
        uint4 uA = *(const uint4*)(xw + pA.x * 64 + 8 * l);
        uint4 uB = *(const uint4*)(xw + pB.x * 64 + 8 * l);
        float wA = __int_as_float(pA.y);
        float wB = __int_as_float(pB.y);
        float fA[8], fB[8];
        bf8_unpack(uA, fA);
        bf8_unpack(uB, fB);
#pragma unroll
        for (int c = 0; c < 8; ++c) {
            a[c] = fmaf(wA, fA[c], a[c]);
            b[c] = fmaf(wB, fB[c], b[c]);
        }
    }
    if (j < end) {
        int2 pA = epack[j];
        uint4 uA = *(const uint4*)(xw + pA.x * 64 + 8 * l);
        float wA = __int_as_float(pA.y);
        float fA[8];
        bf8_unpack(uA, fA);
#pragma unroll
        for (int c = 0; c < 8; ++c) a[c] = fmaf(wA, fA[c], a[c]);
    }
#pragma unroll
    for (int c = 0; c < 8; ++c) {
        a[c] += b[c];
        a[c] += __shfl_xor(a[c], 8);
        a[c] += __shfl_xor(a[c], 16);
        a[c] += __shfl_xor(a[c], 32);
    }
    if (slot == 0) {     // lanes 0..7 write the full 128B row
        float di = dinv[node];
        float d2 = di * di;
        uint4 us = *(const uint4*)(xw + node * 64 + 8 * l);
        float fs[8];
        bf8_unpack(us, fs);
        float4 bv0 = *(const float4*)(bias + 8 * l);
        float4 bv1 = *(const float4*)(bias + 8 * l + 4);
        float o[8];
        o[0] = fmaf(di, a[0], fmaf(d2, fs[0], bv0.x));
        o[1] = fmaf(di, a[1], fmaf(d2, fs[1], bv0.y));
        o[2] = fmaf(di, a[2], fmaf(d2, fs[2], bv0.z));
        o[3] = fmaf(di, a[3], fmaf(d2, fs[3], bv0.w));
        o[4] = fmaf(di, a[4], fmaf(d2, fs[4], bv1.x));
        o[5] = fmaf(di, a[5], fmaf(d2, fs[5], bv1.y));
        o[6] = fmaf(di, a[6], fmaf(d2, fs[6], bv1.z));
        o[7] = fmaf(di, a[7], fmaf(d2, fs[7], bv1.w));
        if (RELU) {
#pragma unroll
            for (int c = 0; c < 8; ++c) o[c] = fmaxf(o[c], 0.f);
        }
        uint4 pk;
        pk.x = (unsigned)fbf(o[0]) | ((unsigned)fbf(o[1]) << 16);
        pk.y = (unsigned)fbf(o[2]) | ((unsigned)fbf(o[3]) << 16);
        pk.z = (unsigned)fbf(o[4]) | ((unsigned)fbf(o[5]) << 16);
        pk.w = (unsigned)fbf(o[6]) | ((unsigned)fbf(o[7]) << 16);
        *(uint4*)(out + node * 64 + 8 * l) = pk;
    }
}

// ---------------- standalone GEMM (layer 2): h1 bf16 @ W2 fp32 -> xw2 bf16 -----------
__global__ __launch_bounds__(256) void gemm64_kernel(const ushort* __restrict__ X,
                                                     const float* __restrict__ W,
                                                     ushort* __restrict__ out) {
    __shared__ float Xs[64][68];
    __shared__ float Ws[64 * 64];
    for (int i = threadIdx.x; i < 64 * 16; i += 256)
        ((float4*)Ws)[i] = ((const float4*)W)[i];
    int tx = threadIdx.x & 15, ty = threadIdx.x >> 4;
    int row0 = blockIdx.x * 64;
    float acc[4][4] = {};
    __syncthreads();
    for (int i = threadIdx.x; i < 512; i += 256) {   // 64 rows x 8 groups of 8 ch
        int r = i >> 3, g = i & 7;
        int gr = row0 + r; if (gr >= NN) gr = NN - 1;
        uint4 v = *(const uint4*)(X + (long long)gr * 64 + g * 8);
        float f[8];
        bf8_unpack(v, f);
        *(float4*)&Xs[r][g * 8] = make_float4(f[0], f[1], f[2], f[3]);
        *(float4*)&Xs[r][g * 8 + 4] = make_float4(f[4], f[5], f[6], f[7]);
    }
    __syncthreads();
#pragma unroll
    for (int k4 = 0; k4 < 16; ++k4) {
        float4 x0 = *(const float4*)&Xs[ty * 4 + 0][k4 * 4];
        float4 x1 = *(const float4*)&Xs[ty * 4 + 1][k4 * 4];
        float4 x2 = *(const float4*)&Xs[ty * 4 + 2][k4 * 4];
        float4 x3 = *(const float4*)&Xs[ty * 4 + 3][k4 * 4];
#pragma unroll
        for (int kk = 0; kk < 4; ++kk) {
            float4 wv = *(const float4*)&Ws[(k4 * 4 + kk) * 64 + tx * 4];
            float xa = (&x0.x)[kk], xb = (&x1.x)[kk], xc = (&x2.x)[kk], xd = (&x3.x)[kk];
            acc[0][0] = fmaf(xa, wv.x, acc[0][0]); acc[0][1] = fmaf(xa, wv.y, acc[0][1]);
            acc[0][2] = fmaf(xa, wv.z, acc[0][2]); acc[0][3] = fmaf(xa, wv.w, acc[0][3]);
            acc[1][0] = fmaf(xb, wv.x, acc[1][0]); acc[1][1] = fmaf(xb, wv.y, acc[1][1]);
            acc[1][2] = fmaf(xb, wv.z, acc[1][2]); acc[1][3] = fmaf(xb, wv.w, acc[1][3]);
            acc[2][0] = fmaf(xc, wv.x, acc[2][0]); acc[2][1] = fmaf(xc, wv.y, acc[2][1]);
            acc[2][2] = fmaf(xc, wv.z, acc[2][2]); acc[2][3] = fmaf(xc, wv.w, acc[2][3]);
            acc[3][0] = fmaf(xd, wv.x, acc[3][0]); acc[3][1] = fmaf(xd, wv.y, acc[3][1]);
            acc[3][2] = fmaf(xd, wv.z, acc[3][2]); acc[3][3] = fmaf(xd, wv.w, acc[3][3]);
        }
    }
#pragma unroll
    for (int j = 0; j < 4; ++j) {
        int r = row0 + ty * 4 + j;
        if (r < NN) {
            ushort4 sv;
            sv.x = fbf(acc[j][0]); sv.y = fbf(acc[j][1]);
            sv.z = fbf(acc[j][2]); sv.w = fbf(acc[j][3]);
            *(ushort4*)(out + (long long)r * 64 + tx * 4) = sv;
        }
    }
}

// ---------------- fused mean-pool + MLP head: 4 waves per graph (h is bf16) -----------
__global__ __launch_bounds__(256) void poolhead_kernel(const ushort* __restrict__ h,
                                                       const int* __restrict__ gbeg,
                                                       const int* __restrict__ gend,
                                                       const float* __restrict__ LW1,
                                                       const float* __restrict__ Lb1,
                                                       const float* __restrict__ LW2,
                                                       const float* __restrict__ Lb2,
                                                       float* __restrict__ out) {
    __shared__ float pp[4][64];
    __shared__ float p[64];
    __shared__ float t1[32];
    int g = blockIdx.x, t = threadIdx.x;
    int lane = t & 63, wid = t >> 6;
    int b = gbeg[g], e = gend[g];
    float acc = 0.f;
    for (int i = b + wid; i < e; i += 4) acc += bfu(h[i * 64 + lane]);
    pp[wid][lane] = acc;
    __syncthreads();
    if (t < 64) {
        float s = pp[0][t] + pp[1][t] + pp[2][t] + pp[3][t];
        p[t] = s / fmaxf((float)(e - b), 1.0f);
    }
    __syncthreads();
    if (t < 32) {
        float a = Lb1[t];
#pragma unroll
        for (int k = 0; k < 64; ++k) a = fmaf(p[k], LW1[k * 32 + t], a);
        t1[t] = a;
    }
    __syncthreads();
    if (t < 10) {
        float a = Lb2[t];
#pragma unroll
        for (int j = 0; j < 32; ++j) a = fmaf(t1[j], LW2[j * 10 + t], a);
        out[g * 10 + t] = a;
    }
}

// ---------------- launch ----------------

extern "C" void kernel_launch(void* const* d_in, const int* in_sizes, int n_in,
                              void* d_out, int out_size, void* d_ws, size_t ws_size,
                              hipStream_t stream) {
    const float* x     = (const float*)d_in[0];
    const int*   ei    = (const int*)d_in[1];   // [2, NE]
    const float* ew    = (const float*)d_in[2];
    const int*   batch = (const int*)d_in[3];
    const float* W1    = (const float*)d_in[4];
    const float* b1    = (const float*)d_in[5];
    const float* W2    = (const float*)d_in[6];
    const float* b2    = (const float*)d_in[7];
    const float* LW1   = (const float*)d_in[8];
    const float* Lb1   = (const float*)d_in[9];
    const float* LW2   = (const float*)d_in[10];
    const float* Lb2   = (const float*)d_in[11];

    const int* src = ei;
    const int* dst = ei + NE;

    // workspace layout (4-byte units)
    float* ws = (float*)d_ws;
    unsigned long long* h64 = (unsigned long long*)ws;  // [NN] ull: 0 .. 100096
    int*   gbeg   = (int*)(ws + 100096);       // [NG] -> 100608
    int*   gend   = (int*)(ws + 100608);       // [NG] -> 101120  (zero range ends here)
    float* dinv   = ws + 101120;               // [NN]   -> 151168
    int*   rowptr = (int*)(ws + 151168);       // [NN+1] -> 201216
    int*   partial= (int*)(ws + 201216);       // [NB]   -> 201472 (8B-aligned next)
    int2*  epack  = (int2*)(ws + 201472);      // [NE]   -> 1801472
    ushort* xwA   = (ushort*)(ws + 1801472);   // [NN*64] bf16: xw1, later xw2 -> 3401472
    ushort* h12   = (ushort*)(ws + 3401472);   // [NN*64] bf16: h1, later h2 -> 5001472
    int*   rank   = (int*)(ws + 5001472);      // [NE] (dead after scatter) -> 5801472
    // total 5801472 floats = 23.2 MB

    zero_kernel<<<(101120 + 255) / 256, 256, 0, stream>>>(ws, 101120);

    // hist64 (1 atomic/edge) co-executing with gemm128 (x @ W1), roles interleaved
    hist_gemm_kernel<<<HG_GRID, 256, 0, stream>>>(dst, ew, h64, rank, x, W1, xwA);
    dinv_scanA_kernel<<<NB, 256, 0, stream>>>(h64, dinv, partial);
    scanC_bounds_kernel<<<NB, 256, 0, stream>>>(h64, partial, rowptr, batch, gbeg, gend);
    scatter_kernel<<<(NE + 255) / 256, 256, 0, stream>>>(src, dst, ew, dinv, rowptr, rank, epack);

    // ---- layer 1 aggregation ----
    agg_kernel<true><<<(NN + 3) / 4, 256, 0, stream>>>(xwA, rowptr, epack, dinv, b1, h12);

    // ---- layer 2 ----
    gemm64_kernel<<<NTILES, 256, 0, stream>>>(h12, W2, xwA);
    agg_kernel<false><<<(NN + 3) / 4, 256, 0, stream>>>(xwA, rowptr, epack, dinv, b2, h12);

    // ---- pool + head ----
    poolhead_kernel<<<NG, 256, 0, stream>>>(h12, gbeg, gend, LW1, Lb1, LW2, Lb2, (float*)d_out);
}